// Round 1
// baseline (526.447 us; speedup 1.0000x reference)
//
#include <hip/hip_runtime.h>

// ---------------------------------------------------------------------------
// DeepCapsNet forward, fp32 baseline.
//   x(512,1,39,39) -> conv1 s2 +bn+relu -> (512,128,19,19)
//   -> conv2 s2 +bn+relu -> (512,256,9,9)
//   -> depthwise conv3 9x9 -> (512,256) -> squash -> 3x fccaps -> (512,10,16)
// Workspace layout (floats):
//   h1:  [0,            23658496)   512*128*361   (94.6 MB)
//   h2:  [23658496,     34275328)   512*256*81    (42.5 MB)
//   wT:  [34275328,     34570240)   1152*256      ( 1.2 MB)
// requires ws_size >= 138,280,960 bytes
// ---------------------------------------------------------------------------

// ---------------- weight transpose: w2(co,k) -> wT(k,co), k=1152, co=256 ----
__global__ __launch_bounds__(256) void k_transpose_w2(
    const float* __restrict__ w2, float* __restrict__ wT) {
    __shared__ float tile[32][33];
    const int kt = blockIdx.x * 32;   // 36 tiles of k
    const int ct = blockIdx.y * 32;   // 8 tiles of co
    const int t  = threadIdx.x;
    const int tk = t & 31, tc = t >> 5;
#pragma unroll
    for (int i = 0; i < 4; ++i)
        tile[tc + i * 8][tk] = w2[(size_t)(ct + tc + i * 8) * 1152 + kt + tk];
    __syncthreads();
    const int tc2 = t & 31, tk2 = t >> 5;
#pragma unroll
    for (int i = 0; i < 4; ++i)
        wT[(size_t)(kt + tk2 + i * 8) * 256 + ct + tc2] = tile[tc2][tk2 + i * 8];
}

// ---------------- conv1 (1->128, 3x3, s2) + bn + relu ----------------------
__global__ __launch_bounds__(256) void k_conv1(
    const float* __restrict__ x, const float* __restrict__ w,
    const float* __restrict__ bias, const float* __restrict__ g,
    const float* __restrict__ bb, const float* __restrict__ bm,
    const float* __restrict__ bv, float* __restrict__ h1) {
    __shared__ __align__(16) float xs[1521];        // 39*39 image
    __shared__ __align__(16) float wls[128 * 12];   // 9 weights padded to 12
    __shared__ __align__(8)  float2 scsh[128];      // bn scale/shift
    const int b = blockIdx.x, t = threadIdx.x;
    const float* xb = x + (size_t)b * 1521;
    for (int i = t; i < 1521; i += 256) xs[i] = xb[i];
    for (int i = t; i < 1152; i += 256) wls[(i / 9) * 12 + (i % 9)] = w[i];
    if (t < 128) {
        const float inv = g[t] * rsqrtf(bv[t] + 1e-5f);
        scsh[t] = make_float2(inv, bias[t] * inv + bb[t] - bm[t] * inv);
    }
    __syncthreads();
    float* outb = h1 + (size_t)b * 46208;           // 128*361
    for (int p = t; p < 361; p += 256) {
        const int oh = p / 19, ow = p % 19;
        const int base = oh * 78 + ow * 2;          // (2*oh)*39 + 2*ow
        const float x0 = xs[base],      x1 = xs[base + 1],  x2 = xs[base + 2];
        const float x3 = xs[base + 39], x4 = xs[base + 40], x5 = xs[base + 41];
        const float x6 = xs[base + 78], x7 = xs[base + 79], x8 = xs[base + 80];
        for (int c = 0; c < 128; ++c) {
            const float4 wa = *(const float4*)(wls + c * 12);
            const float4 wc = *(const float4*)(wls + c * 12 + 4);
            const float  w8 = wls[c * 12 + 8];
            float acc = x0 * wa.x + x1 * wa.y + x2 * wa.z + x3 * wa.w +
                        x4 * wc.x + x5 * wc.y + x6 * wc.z + x7 * wc.w + x8 * w8;
            const float2 ss = scsh[c];
            outb[c * 361 + p] = fmaxf(fmaf(acc, ss.x, ss.y), 0.0f);
        }
    }
}

// ---------------- conv2 (128->256, 3x3, s2) + bn + relu as implicit GEMM ---
// M = 512*81 = 41472 (rows: b,oh,ow), N = 256 (co), K = 1152 (ci,kh,kw)
// tile 128x128, BK=36 (=4 ci * 9 taps), 256 threads, 8x8 acc / thread
__global__ __launch_bounds__(256) void k_conv2(
    const float* __restrict__ h1, const float* __restrict__ wT,
    const float* __restrict__ bias, const float* __restrict__ g,
    const float* __restrict__ bb, const float* __restrict__ bm,
    const float* __restrict__ bv, float* __restrict__ h2) {
    __shared__ __align__(16) float As[36][128];
    __shared__ __align__(16) float Bs[36][128];
    const int t  = threadIdx.x;
    const int tx = t & 15, ty = t >> 4;
    const int m0  = blockIdx.y * 128;   // 324
    const int co0 = blockIdx.x * 128;   // 2

    // Precompute A-gather bases. k = 36*ks + kk with 36 % 9 == 0, so the
    // (kh,kw) part of k is invariant across ks and ci advances by exactly 4:
    //   addr = [bi*46208 + 38*oh + 2*ow + ci0*361 + 19*kh + kw] + ks*1444
    int aaddr[18];
#pragma unroll
    for (int f = 0; f < 18; ++f) {
        const int e  = t + f * 256;
        const int kk = e >> 7, r = e & 127;
        const int ci0 = kk / 9, q = kk - ci0 * 9;
        const int kh = q / 3, kw = q - kh * 3;
        const int gm = m0 + r;
        const int bi = gm / 81, p = gm - bi * 81;
        const int oh = p / 9,  ow = p - oh * 9;
        aaddr[f] = bi * 46208 + 38 * oh + 2 * ow + ci0 * 361 + 19 * kh + kw;
    }

    float acc[8][8];
#pragma unroll
    for (int i = 0; i < 8; ++i)
#pragma unroll
        for (int j = 0; j < 8; ++j) acc[i][j] = 0.0f;

    float* Afl = &As[0][0];
    float* Bfl = &Bs[0][0];
    for (int ks = 0; ks < 32; ++ks) {
        __syncthreads();
#pragma unroll
        for (int f = 0; f < 18; ++f) {
            const int e = t + f * 256;
            Afl[e] = h1[aaddr[f] + ks * 1444];
            // Bs[kk][co_local]: wT[(36*ks+kk)*256 + co0 + co_local]
            Bfl[e] = wT[e + (e & 0xFFFFFF80) + co0 + ks * 9216];
        }
        __syncthreads();
#pragma unroll
        for (int kk = 0; kk < 36; ++kk) {
            float av[8], bw[8];
            *(float4*)&av[0] = *(const float4*)&As[kk][ty * 8];
            *(float4*)&av[4] = *(const float4*)&As[kk][ty * 8 + 4];
            *(float4*)&bw[0] = *(const float4*)&Bs[kk][tx * 8];
            *(float4*)&bw[4] = *(const float4*)&Bs[kk][tx * 8 + 4];
#pragma unroll
            for (int i = 0; i < 8; ++i)
#pragma unroll
                for (int j = 0; j < 8; ++j)
                    acc[i][j] = fmaf(av[i], bw[j], acc[i][j]);
        }
    }

    // epilogue: bn + relu, store h2[b][co][p]
    float sc[8], sh[8];
#pragma unroll
    for (int j = 0; j < 8; ++j) {
        const int co = co0 + tx * 8 + j;
        const float inv = g[co] * rsqrtf(bv[co] + 1e-5f);
        sc[j] = inv;
        sh[j] = bias[co] * inv + bb[co] - bm[co] * inv;
    }
#pragma unroll
    for (int i = 0; i < 8; ++i) {
        const int gm = m0 + ty * 8 + i;
        const int bi = gm / 81, p = gm - bi * 81;
        float* op = h2 + (size_t)bi * 20736 + p;
#pragma unroll
        for (int j = 0; j < 8; ++j) {
            const int co = co0 + tx * 8 + j;
            op[co * 81] = fmaxf(fmaf(acc[i][j], sc[j], sh[j]), 0.0f);
        }
    }
}

// ---------------- fused conv3(depthwise) + squash + 3x fccaps --------------
// one block per batch element; everything LDS-resident.
// fccaps math (verified vs einsums):
//   U_hat[i,k,l] = sum_j U[i,j] * W[i,k,j,l]
//   S[k,l]       = sum_i U_hat[i,k,l]
//   A_sum[h,k]   = sum_l U_hat[h,k,l] * S[k,l]
//   C            = softmax_k(A_sum / 2.8284271)
//   U_h[k,l]     = sum_i U_hat[i,k,l] * C[i,k]  -> squash
__device__ __forceinline__ void fccaps_block(
    const int n_l, const int n_h, const int d_h, const float* __restrict__ Wg,
    float* U, float* Uh, float* Sv, float* Av, float* Cv, float* coefs,
    float* outU, const int t) {
    const int nkd = n_h * d_h;
    const int total = n_l * nkd;
    __syncthreads();                       // U ready / Uh free
    for (int e = t; e < total; e += 256) {
        const int i = e / nkd, rem = e - i * nkd;
        const int k = rem / d_h, l = rem - k * d_h;
        const float* wp = Wg + (size_t)((i * n_h + k) * 8) * d_h + l;
        const float* up = U + i * 8;
        float acc = 0.0f;
#pragma unroll
        for (int j = 0; j < 8; ++j) acc += up[j] * wp[j * d_h];
        Uh[e] = acc;
    }
    __syncthreads();
    for (int e = t; e < nkd; e += 256) {   // S
        float acc = 0.0f;
        for (int i = 0; i < n_l; ++i) acc += Uh[i * nkd + e];
        Sv[e] = acc;
    }
    __syncthreads();
    for (int e = t; e < n_l * n_h; e += 256) {  // A_sum
        const int h = e / n_h, k = e - h * n_h;
        float acc = 0.0f;
        for (int l = 0; l < d_h; ++l)
            acc += Uh[h * nkd + k * d_h + l] * Sv[k * d_h + l];
        Av[e] = acc;
    }
    __syncthreads();
    if (t < n_l) {                          // softmax over k, row t
        const float invs = 1.0f / 2.8284271247461903f;
        float mx = -1e30f;
        for (int k = 0; k < n_h; ++k) mx = fmaxf(mx, Av[t * n_h + k]);
        float sum = 0.0f;
        for (int k = 0; k < n_h; ++k) {
            const float ev = expf((Av[t * n_h + k] - mx) * invs);
            Cv[t * n_h + k] = ev;
            sum += ev;
        }
        const float r = 1.0f / sum;
        for (int k = 0; k < n_h; ++k) Cv[t * n_h + k] *= r;
    }
    __syncthreads();
    for (int e = t; e < nkd; e += 256) {    // U_h (reuse Sv)
        const int k = e / d_h;
        float acc = 0.0f;
        for (int i = 0; i < n_l; ++i) acc += Uh[i * nkd + e] * Cv[i * n_h + k];
        Sv[e] = acc;
    }
    __syncthreads();
    if (t < n_h) {                          // squash coefficients
        float ssq = 0.0f;
        for (int l = 0; l < d_h; ++l) { const float uv = Sv[t * d_h + l]; ssq += uv * uv; }
        const float n = sqrtf(ssq);
        coefs[t] = (1.0f - 1.0f / (expf(n) + 1e-20f)) / (n + 1e-20f);
    }
    __syncthreads();
    for (int e = t; e < nkd; e += 256) outU[e] = Sv[e] * coefs[e / d_h];
}

__global__ __launch_bounds__(256) void k_caps(
    const float* __restrict__ h2, const float* __restrict__ w3,
    const float* __restrict__ b3, const float* __restrict__ W1,
    const float* __restrict__ W2, const float* __restrict__ W3,
    float* __restrict__ out) {
    __shared__ float U[256];
    __shared__ float Uh[8192];
    __shared__ float Sv[256];
    __shared__ float Av[1024];
    __shared__ float Cv[1024];
    __shared__ float coefs[32];
    const int b = blockIdx.x, t = threadIdx.x;
    {   // depthwise conv3 + bias: U[c] = <h2[b,c,:], w3[c,:]> + b3[c]
        const float* hr = h2 + (size_t)b * 20736 + t * 81;
        const float* wr = w3 + t * 81;
        float acc = 0.0f;
        for (int p = 0; p < 81; ++p) acc += hr[p] * wr[p];
        U[t] = acc + b3[t];
    }
    __syncthreads();
    if (t < 32) {   // squash the 32 primary capsules (dim 8)
        float ssq = 0.0f;
        for (int j = 0; j < 8; ++j) { const float uv = U[t * 8 + j]; ssq += uv * uv; }
        const float n = sqrtf(ssq);
        coefs[t] = (1.0f - 1.0f / (expf(n) + 1e-20f)) / (n + 1e-20f);
    }
    __syncthreads();
    U[t] *= coefs[t >> 3];
    fccaps_block(32, 32,  8, W1, U, Uh, Sv, Av, Cv, coefs, U, t);
    fccaps_block(32, 32,  8, W2, U, Uh, Sv, Av, Cv, coefs, U, t);
    fccaps_block(32, 10, 16, W3, U, Uh, Sv, Av, Cv, coefs, out + (size_t)b * 160, t);
}

// ---------------------------------------------------------------------------
extern "C" void kernel_launch(void* const* d_in, const int* in_sizes, int n_in,
                              void* d_out, int out_size, void* d_ws, size_t ws_size,
                              hipStream_t stream) {
    const float* x    = (const float*)d_in[0];
    const float* c1w  = (const float*)d_in[1];
    const float* c1b  = (const float*)d_in[2];
    const float* bn1g = (const float*)d_in[3];
    const float* bn1b = (const float*)d_in[4];
    const float* bn1m = (const float*)d_in[5];
    const float* bn1v = (const float*)d_in[6];
    const float* c2w  = (const float*)d_in[7];
    const float* c2b  = (const float*)d_in[8];
    const float* bn2g = (const float*)d_in[9];
    const float* bn2b = (const float*)d_in[10];
    const float* bn2m = (const float*)d_in[11];
    const float* bn2v = (const float*)d_in[12];
    const float* c3w  = (const float*)d_in[13];
    const float* c3b  = (const float*)d_in[14];
    const float* W1   = (const float*)d_in[15];
    const float* W2   = (const float*)d_in[16];
    const float* W3   = (const float*)d_in[17];
    float* out = (float*)d_out;
    float* ws  = (float*)d_ws;

    float* h1 = ws;                  // 23,658,496 floats
    float* h2 = ws + 23658496;       // 10,616,832 floats
    float* wT = ws + 34275328;       //    294,912 floats

    k_transpose_w2<<<dim3(36, 8), 256, 0, stream>>>(c2w, wT);
    k_conv1<<<dim3(512), 256, 0, stream>>>(x, c1w, c1b, bn1g, bn1b, bn1m, bn1v, h1);
    k_conv2<<<dim3(2, 324), 256, 0, stream>>>(h1, wT, c2b, bn2g, bn2b, bn2m, bn2v, h2);
    k_caps<<<dim3(512), 256, 0, stream>>>(h2, c3w, c3b, W1, W2, W3, out);
}

// Round 2
// 334.186 us; speedup vs baseline: 1.5753x; 1.5753x over previous
//
#include <hip/hip_runtime.h>

// ---------------------------------------------------------------------------
// DeepCapsNet forward, conv2 on MFMA via 2-way bf16 split (hh+hl+lh).
// Workspace layout (dwords):
//   h1e:  [0,         12451840)  u32 packed(hi<<16|lo), [bi][ci][ih][10] (iw even)
//   h1o:  [12451840,  23658496)  u32 packed,            [bi][ci][ih][9]  (iw odd)
//   h2 :  [23658496,  34275328)  f32, layout [b][p=81][co=256]
//   Bt :  [34275328,  34643968)  u32, pre-tiled B LDS images: [s*2+cot][hi/lo][n=128][20]
//   w3T:  [34643968,  34664704)  f32, [p=81][c=256]
// total 138,658,816 bytes
// ---------------------------------------------------------------------------

typedef __attribute__((ext_vector_type(8))) short short8;   // 8 bf16 (4 VGPRs)
typedef __attribute__((ext_vector_type(4))) float f32x4;

__device__ __forceinline__ ushort f2bf(float x) {
    uint u = __float_as_uint(x);
    return (ushort)((u + 0x7FFFu + ((u >> 16) & 1u)) >> 16);
}
__device__ __forceinline__ void bfsplit(float x, ushort& h, ushort& l) {
    h = f2bf(x);
    float hf = __uint_as_float(((uint)h) << 16);
    l = f2bf(x - hf);
}

// ---------------- prep: w2(co,k) -> Bt pre-tiled bf16 hi/lo LDS images -----
// K reordered as k' = tap*128 + ci (tap = kh*3+kw). Step s: tap=s>>2,
// ci = (s&3)*32 + kk. Bt[(s*2+cot)]: [hi 2560 dw][lo 2560 dw], row n: 20 dw.
__global__ __launch_bounds__(256) void k_prep_b(
    const float* __restrict__ w2, uint* __restrict__ Bt) {
    const int s = blockIdx.x, cot = blockIdx.y, t = threadIdx.x;
    const int co0 = cot * 128;
    const int n = t & 127, kk0 = (t >> 7) * 16;
    const int tap = s >> 2, cib = (s & 3) * 32;
    uint* dst = Bt + (s * 2 + cot) * 5120;
#pragma unroll
    for (int f = 0; f < 8; ++f) {
        const int kk = kk0 + 2 * f;
        const int ci = cib + kk;
        const float a0 = w2[(size_t)(co0 + n) * 1152 + ci * 9 + tap];
        const float a1 = w2[(size_t)(co0 + n) * 1152 + (ci + 1) * 9 + tap];
        ushort h0, l0, h1, l1;
        bfsplit(a0, h0, l0);
        bfsplit(a1, h1, l1);
        dst[n * 20 + (kk >> 1)]        = (uint)h0 | ((uint)h1 << 16);
        dst[2560 + n * 20 + (kk >> 1)] = (uint)l0 | ((uint)l1 << 16);
    }
}

// ---------------- prep: w3(c,81) -> w3T(p,c) -------------------------------
__global__ __launch_bounds__(256) void k_prep_w3(
    const float* __restrict__ w3, float* __restrict__ w3T) {
    const int p = blockIdx.x, t = threadIdx.x;
    w3T[p * 256 + t] = w3[t * 81 + p];
}

// ---------------- conv1 (1->128, 3x3, s2) + bn + relu, packed bf16 out -----
__global__ __launch_bounds__(256) void k_conv1(
    const float* __restrict__ x, const float* __restrict__ w,
    const float* __restrict__ bias, const float* __restrict__ g,
    const float* __restrict__ bb, const float* __restrict__ bm,
    const float* __restrict__ bv,
    uint* __restrict__ h1e, uint* __restrict__ h1o) {
    __shared__ __align__(16) float xs[1521];
    __shared__ float wls[16 * 12];
    __shared__ float2 scsh[16];
    const int b = blockIdx.x, c0 = blockIdx.y * 16, t = threadIdx.x;
    const float* xb = x + (size_t)b * 1521;
    for (int i = t; i < 1521; i += 256) xs[i] = xb[i];
    if (t < 144) wls[(t / 9) * 12 + (t % 9)] = w[(c0 + t / 9) * 9 + t % 9];
    if (t < 16) {
        const int c = c0 + t;
        const float inv = g[c] * rsqrtf(bv[c] + 1e-5f);
        scsh[t] = make_float2(inv, bias[c] * inv + bb[c] - bm[c] * inv);
    }
    __syncthreads();
#pragma unroll
    for (int f = 0; f < 2; ++f) {
        const int p = t + 256 * f;
        if (p >= 361) break;
        const int y = p / 19, xq = p - y * 19;
        const int base = y * 78 + xq * 2;
        const float x0 = xs[base],      x1 = xs[base + 1],  x2 = xs[base + 2];
        const float x3 = xs[base + 39], x4 = xs[base + 40], x5 = xs[base + 41];
        const float x6 = xs[base + 78], x7 = xs[base + 79], x8 = xs[base + 80];
        const int even = ((xq & 1) == 0);
        const int xi = xq >> 1;
#pragma unroll
        for (int c = 0; c < 16; ++c) {
            const float* wp = wls + c * 12;
            float acc = x0 * wp[0] + x1 * wp[1] + x2 * wp[2] + x3 * wp[3] +
                        x4 * wp[4] + x5 * wp[5] + x6 * wp[6] + x7 * wp[7] + x8 * wp[8];
            const float2 ss = scsh[c];
            const float v = fmaxf(fmaf(acc, ss.x, ss.y), 0.0f);
            ushort hs, ls;
            bfsplit(v, hs, ls);
            const uint pk = ((uint)hs << 16) | (uint)ls;
            const int cc = b * 128 + c0 + c;
            if (even) h1e[(cc * 19 + y) * 10 + xi] = pk;
            else      h1o[(cc * 19 + y) * 9 + xi]  = pk;
        }
    }
}

// ---------------- conv2 as MFMA GEMM (bf16 split), M=41472 N=256 K=1152 ----
// tile 128x128, BK=32 (step s: tap=s>>2 fixed, ci block of 32), 4 waves,
// wave tile 64x64 = 4x4 MFMA 16x16x32 tiles, 3 MFMAs (hh,hl,lh) per tile.
// LDS dword map: A_hi [0,2560) A_lo [2560,5120) B_hi [5120,7680) B_lo [7680,10240)
// rows: 20 dwords (40 bf16; 16B-aligned, conflict-free b128 frags)
__global__ __launch_bounds__(256) void k_conv2(
    const uint* __restrict__ h1e, const uint* __restrict__ h1o,
    const uint* __restrict__ Bt,
    const float* __restrict__ bias, const float* __restrict__ g,
    const float* __restrict__ bb, const float* __restrict__ bm,
    const float* __restrict__ bv, float* __restrict__ h2) {
    __shared__ uint ldsu[10240];
    const int t = threadIdx.x;
    const int lane = t & 63, wave = t >> 6;
    const int wm = (wave >> 1) * 64, wn = (wave & 1) * 64;
    const int ln15 = lane & 15, lq = lane >> 4;
    const int M0 = blockIdx.y * 128, cot = blockIdx.x, co0 = cot * 128;

    // A staging ownership: m = (t&15) + 16f (f=0..7), kk = 2*(t>>4)
    const int kk = (t >> 4) * 2;
    int eb[8], ob[8];
#pragma unroll
    for (int f = 0; f < 8; ++f) {
        const int gm = M0 + (t & 15) + 16 * f;
        const int bi = gm / 81, p = gm - bi * 81;
        const int oh = p / 9, ow = p - oh * 9;
        eb[f] = bi * 24320 + oh * 20 + ow;   // bi*(128*190) + (2oh)*10 + ow
        ob[f] = bi * 21888 + oh * 18 + ow;   // bi*(128*171) + (2oh)*9  + ow
    }

    f32x4 acc[4][4] = {};

    for (int s = 0; s < 36; ++s) {
        const int tap = s >> 2, ci0 = (s & 3) * 32;
        const int kh = tap / 3, kw = tap - kh * 3;
        const int odd = kw & 1;
        const uint* __restrict__ src = odd ? h1o : h1e;
        const int CW = odd ? 171 : 190;
        const int cbase = (ci0 + kk) * CW + (odd ? kh * 9 : (kh * 10 + (kw >> 1)));
        __syncthreads();
        // ---- A stage
#pragma unroll
        for (int f = 0; f < 8; ++f) {
            const int base = (odd ? ob[f] : eb[f]) + cbase;
            const uint v0 = src[base];
            const uint v1 = src[base + CW];
            const uint hiw = (v0 >> 16) | (v1 & 0xFFFF0000u);
            const uint low = (v0 & 0xFFFFu) | (v1 << 16);
            const int m = (t & 15) + 16 * f;
            ldsu[m * 20 + (kk >> 1)]        = hiw;
            ldsu[2560 + m * 20 + (kk >> 1)] = low;
        }
        // ---- B stage: straight copy of pre-tiled image
        const uint* bsrc = Bt + (s * 2 + cot) * 5120;
#pragma unroll
        for (int f = 0; f < 20; ++f) ldsu[5120 + t + 256 * f] = bsrc[t + 256 * f];
        __syncthreads();
        // ---- fragments + MFMA
        short8 ah[4], al[4], bh[4], bl[4];
#pragma unroll
        for (int i = 0; i < 4; ++i) {
            const int row = wm + i * 16 + ln15;
            ah[i] = *reinterpret_cast<const short8*>(ldsu + row * 20 + lq * 4);
            al[i] = *reinterpret_cast<const short8*>(ldsu + 2560 + row * 20 + lq * 4);
        }
#pragma unroll
        for (int j = 0; j < 4; ++j) {
            const int row = wn + j * 16 + ln15;
            bh[j] = *reinterpret_cast<const short8*>(ldsu + 5120 + row * 20 + lq * 4);
            bl[j] = *reinterpret_cast<const short8*>(ldsu + 7680 + row * 20 + lq * 4);
        }
#pragma unroll
        for (int i = 0; i < 4; ++i)
#pragma unroll
            for (int j = 0; j < 4; ++j) {
                acc[i][j] = __builtin_amdgcn_mfma_f32_16x16x32_bf16(ah[i], bh[j], acc[i][j], 0, 0, 0);
                acc[i][j] = __builtin_amdgcn_mfma_f32_16x16x32_bf16(ah[i], bl[j], acc[i][j], 0, 0, 0);
                acc[i][j] = __builtin_amdgcn_mfma_f32_16x16x32_bf16(al[i], bh[j], acc[i][j], 0, 0, 0);
            }
    }

    // ---- epilogue: bn + relu, h2[b][p][co]
    float scj[4], shj[4];
#pragma unroll
    for (int j = 0; j < 4; ++j) {
        const int co = co0 + wn + j * 16 + ln15;
        const float inv = g[co] * rsqrtf(bv[co] + 1e-5f);
        scj[j] = inv;
        shj[j] = bias[co] * inv + bb[co] - bm[co] * inv;
    }
#pragma unroll
    for (int i = 0; i < 4; ++i)
#pragma unroll
        for (int r = 0; r < 4; ++r) {
            const int gm = M0 + wm + i * 16 + lq * 4 + r;
            const int bi = gm / 81, p = gm - bi * 81;
            float* op = h2 + (size_t)bi * 20736 + p * 256;
#pragma unroll
            for (int j = 0; j < 4; ++j) {
                const int co = co0 + wn + j * 16 + ln15;
                op[co] = fmaxf(fmaf(acc[i][j][r], scj[j], shj[j]), 0.0f);
            }
        }
}

// ---------------- fused conv3(depthwise) + squash + 3x fccaps --------------
__device__ __forceinline__ void fccaps_block(
    const int n_l, const int n_h, const int d_h, const float* __restrict__ Wg,
    float* U, float* Uh, float* Sv, float* Av, float* Cv, float* coefs,
    float* outU, const int t) {
    const int nkd = n_h * d_h;
    const int total = n_l * nkd;
    __syncthreads();
    for (int e = t; e < total; e += 256) {
        const int i = e / nkd, rem = e - i * nkd;
        const int k = rem / d_h, l = rem - k * d_h;
        const float* wp = Wg + (size_t)((i * n_h + k) * 8) * d_h + l;
        const float* up = U + i * 8;
        float acc = 0.0f;
#pragma unroll
        for (int j = 0; j < 8; ++j) acc += up[j] * wp[j * d_h];
        Uh[e] = acc;
    }
    __syncthreads();
    for (int e = t; e < nkd; e += 256) {
        float acc = 0.0f;
        for (int i = 0; i < n_l; ++i) acc += Uh[i * nkd + e];
        Sv[e] = acc;
    }
    __syncthreads();
    for (int e = t; e < n_l * n_h; e += 256) {
        const int h = e / n_h, k = e - h * n_h;
        float acc = 0.0f;
        for (int l = 0; l < d_h; ++l)
            acc += Uh[h * nkd + k * d_h + l] * Sv[k * d_h + l];
        Av[e] = acc;
    }
    __syncthreads();
    if (t < n_l) {
        const float invs = 1.0f / 2.8284271247461903f;
        float mx = -1e30f;
        for (int k = 0; k < n_h; ++k) mx = fmaxf(mx, Av[t * n_h + k]);
        float sum = 0.0f;
        for (int k = 0; k < n_h; ++k) {
            const float ev = expf((Av[t * n_h + k] - mx) * invs);
            Cv[t * n_h + k] = ev;
            sum += ev;
        }
        const float r = 1.0f / sum;
        for (int k = 0; k < n_h; ++k) Cv[t * n_h + k] *= r;
    }
    __syncthreads();
    for (int e = t; e < nkd; e += 256) {
        const int k = e / d_h;
        float acc = 0.0f;
        for (int i = 0; i < n_l; ++i) acc += Uh[i * nkd + e] * Cv[i * n_h + k];
        Sv[e] = acc;
    }
    __syncthreads();
    if (t < n_h) {
        float ssq = 0.0f;
        for (int l = 0; l < d_h; ++l) { const float uv = Sv[t * d_h + l]; ssq += uv * uv; }
        const float n = sqrtf(ssq);
        coefs[t] = (1.0f - 1.0f / (expf(n) + 1e-20f)) / (n + 1e-20f);
    }
    __syncthreads();
    for (int e = t; e < nkd; e += 256) outU[e] = Sv[e] * coefs[e / d_h];
}

__global__ __launch_bounds__(256) void k_caps(
    const float* __restrict__ h2, const float* __restrict__ w3T,
    const float* __restrict__ b3, const float* __restrict__ W1,
    const float* __restrict__ W2, const float* __restrict__ W3,
    float* __restrict__ out) {
    __shared__ float U[256];
    __shared__ float Uh[8192];
    __shared__ float Sv[256];
    __shared__ float Av[1024];
    __shared__ float Cv[1024];
    __shared__ float coefs[32];
    const int b = blockIdx.x, t = threadIdx.x;
    {   // depthwise conv3: coalesced via [b][p][co] layout + w3T[p][c]
        const float* hr = h2 + (size_t)b * 20736;
        float acc = 0.0f;
        for (int p = 0; p < 81; ++p) acc += hr[p * 256 + t] * w3T[p * 256 + t];
        U[t] = acc + b3[t];
    }
    __syncthreads();
    if (t < 32) {
        float ssq = 0.0f;
        for (int j = 0; j < 8; ++j) { const float uv = U[t * 8 + j]; ssq += uv * uv; }
        const float n = sqrtf(ssq);
        coefs[t] = (1.0f - 1.0f / (expf(n) + 1e-20f)) / (n + 1e-20f);
    }
    __syncthreads();
    U[t] *= coefs[t >> 3];
    fccaps_block(32, 32,  8, W1, U, Uh, Sv, Av, Cv, coefs, U, t);
    fccaps_block(32, 32,  8, W2, U, Uh, Sv, Av, Cv, coefs, U, t);
    fccaps_block(32, 10, 16, W3, U, Uh, Sv, Av, Cv, coefs, out + (size_t)b * 160, t);
}

// ---------------------------------------------------------------------------
extern "C" void kernel_launch(void* const* d_in, const int* in_sizes, int n_in,
                              void* d_out, int out_size, void* d_ws, size_t ws_size,
                              hipStream_t stream) {
    const float* x    = (const float*)d_in[0];
    const float* c1w  = (const float*)d_in[1];
    const float* c1b  = (const float*)d_in[2];
    const float* bn1g = (const float*)d_in[3];
    const float* bn1b = (const float*)d_in[4];
    const float* bn1m = (const float*)d_in[5];
    const float* bn1v = (const float*)d_in[6];
    const float* c2w  = (const float*)d_in[7];
    const float* c2b  = (const float*)d_in[8];
    const float* bn2g = (const float*)d_in[9];
    const float* bn2b = (const float*)d_in[10];
    const float* bn2m = (const float*)d_in[11];
    const float* bn2v = (const float*)d_in[12];
    const float* c3w  = (const float*)d_in[13];
    const float* c3b  = (const float*)d_in[14];
    const float* W1   = (const float*)d_in[15];
    const float* W2   = (const float*)d_in[16];
    const float* W3   = (const float*)d_in[17];
    float* out = (float*)d_out;
    uint*  wsu = (uint*)d_ws;
    float* wsf = (float*)d_ws;

    uint*  h1e = wsu;                    // 12,451,840 dw
    uint*  h1o = wsu + 12451840;         // 11,206,656 dw
    float* h2  = wsf + 23658496;         // 10,616,832 dw
    uint*  Bt  = wsu + 34275328;         //    368,640 dw
    float* w3T = wsf + 34643968;         //     20,736 dw

    k_prep_b<<<dim3(36, 2), 256, 0, stream>>>(c2w, Bt);
    k_prep_w3<<<dim3(81), 256, 0, stream>>>(c3w, w3T);
    k_conv1<<<dim3(512, 8), 256, 0, stream>>>(x, c1w, c1b, bn1g, bn1b, bn1m, bn1v, h1e, h1o);
    k_conv2<<<dim3(2, 324), 256, 0, stream>>>(h1e, h1o, Bt, c2b, bn2g, bn2b, bn2m, bn2v, h2);
    k_caps<<<dim3(512), 256, 0, stream>>>(h2, w3T, c3b, W1, W2, W3, out);
}

// Round 3
// 292.669 us; speedup vs baseline: 1.7988x; 1.1419x over previous
//
#include <hip/hip_runtime.h>

// ---------------------------------------------------------------------------
// DeepCapsNet forward. conv2 = MFMA (bf16 hh+hl+lh split) with tap-reuse:
// raw image chunk staged to LDS once, A-fragments built from LDS for all 9
// taps; B fragments loaded directly from L2-resident pre-tiled Bt.
// Workspace layout (dwords):
//   h1e: [0,        12451840)  u32 packed(hi<<16|lo), [bi][ci][ih(19)][10] (iw even)
//   h1o: [12451840, 23855104)  u32 packed, [bi][ci][19*9 rows +3 pad] stride 174
//   h2 : [23855104, 34471936)  f32, [b][p=81][co=256]
//   Bt : [34471936, 34766848)  u32, [sidx=chunk*9+tap][cot][hi/lo][n=128][16dw]
//   w3T: [34766848, 34787584)  f32, [p=81][c=256]
// total 139,150,336 bytes
// ---------------------------------------------------------------------------

typedef __attribute__((ext_vector_type(8))) short short8;   // 8 bf16
typedef __attribute__((ext_vector_type(4))) float f32x4;
typedef __attribute__((ext_vector_type(4))) uint uint4e;

__device__ __forceinline__ ushort f2bf(float x) {
    uint u = __float_as_uint(x);
    return (ushort)((u + 0x7FFFu + ((u >> 16) & 1u)) >> 16);
}
__device__ __forceinline__ void bfsplit(float x, ushort& h, ushort& l) {
    h = f2bf(x);
    float hf = __uint_as_float(((uint)h) << 16);
    l = f2bf(x - hf);
}
__device__ __forceinline__ short8 mk8(uint a, uint b, uint c, uint d) {
    uint4e v = {a, b, c, d};
    return __builtin_bit_cast(short8, v);
}

// ---------------- prep: w2 -> Bt pre-tiled bf16 hi/lo fragment images ------
// K-step sidx = chunk*9+tap covers k = (ci = chunk*32 + ci_local, tap).
// Bt[sidx][cot][h][n][d]: dw d packs ci_local (2d, 2d+1); n = co_local.
__global__ __launch_bounds__(256) void k_prep_b(
    const float* __restrict__ w2, uint* __restrict__ Bt) {
    __shared__ __align__(16) float wbuf[64 * 288];
    const int sidx = blockIdx.x;          // 0..35
    const int coq  = blockIdx.y;          // 0..3 (64-co quarters)
    const int t = threadIdx.x;
    const int chunk = sidx / 9, tap = sidx - chunk * 9;
    const int co0 = coq * 64;
    // coalesced load: rows co0..co0+63, k-span [chunk*288, chunk*288+288)
    for (int idx = t; idx < 4608; idx += 256) {
        const int n = idx / 72, q = idx - n * 72;
        ((float4*)wbuf)[n * 72 + q] =
            *(const float4*)(w2 + (size_t)(co0 + n) * 1152 + chunk * 288 + q * 4);
    }
    __syncthreads();
    const int n = t & 63, dg = (t >> 6) * 4;
    const int cot = coq >> 1, nn = ((coq & 1) * 64) + n;
    uint* dst = Bt + (size_t)(sidx * 2 + cot) * 4096;
#pragma unroll
    for (int dd = 0; dd < 4; ++dd) {
        const int d = dg + dd;
        const float x = wbuf[n * 288 + (2 * d) * 9 + tap];
        const float y = wbuf[n * 288 + (2 * d + 1) * 9 + tap];
        ushort xh, xl, yh, yl;
        bfsplit(x, xh, xl);
        bfsplit(y, yh, yl);
        dst[nn * 16 + d]        = (uint)xh | ((uint)yh << 16);
        dst[2048 + nn * 16 + d] = (uint)xl | ((uint)yl << 16);
    }
}

// ---------------- prep: w3(c,81) -> w3T(p,c) -------------------------------
__global__ __launch_bounds__(256) void k_prep_w3(
    const float* __restrict__ w3, float* __restrict__ w3T) {
    const int p = blockIdx.x, t = threadIdx.x;
    w3T[p * 256 + t] = w3[t * 81 + p];
}

// ---------------- conv1 (1->128, 3x3, s2) + bn + relu, packed bf16 out -----
__global__ __launch_bounds__(256) void k_conv1(
    const float* __restrict__ x, const float* __restrict__ w,
    const float* __restrict__ bias, const float* __restrict__ g,
    const float* __restrict__ bb, const float* __restrict__ bm,
    const float* __restrict__ bv,
    uint* __restrict__ h1e, uint* __restrict__ h1o) {
    __shared__ __align__(16) float xs[1521];
    __shared__ float wls[16 * 12];
    __shared__ float2 scsh[16];
    const int b = blockIdx.x, c0 = blockIdx.y * 16, t = threadIdx.x;
    const float* xb = x + (size_t)b * 1521;
    for (int i = t; i < 1521; i += 256) xs[i] = xb[i];
    if (t < 144) wls[(t / 9) * 12 + (t % 9)] = w[(c0 + t / 9) * 9 + t % 9];
    if (t < 16) {
        const int c = c0 + t;
        const float inv = g[c] * rsqrtf(bv[c] + 1e-5f);
        scsh[t] = make_float2(inv, bias[c] * inv + bb[c] - bm[c] * inv);
    }
    __syncthreads();
#pragma unroll
    for (int f = 0; f < 2; ++f) {
        const int p = t + 256 * f;
        if (p >= 361) break;
        const int y = p / 19, xq = p - y * 19;
        const int base = y * 78 + xq * 2;
        const float x0 = xs[base],      x1 = xs[base + 1],  x2 = xs[base + 2];
        const float x3 = xs[base + 39], x4 = xs[base + 40], x5 = xs[base + 41];
        const float x6 = xs[base + 78], x7 = xs[base + 79], x8 = xs[base + 80];
        const int even = ((xq & 1) == 0);
        const int xi = xq >> 1;
#pragma unroll
        for (int c = 0; c < 16; ++c) {
            const float* wp = wls + c * 12;
            float acc = x0 * wp[0] + x1 * wp[1] + x2 * wp[2] + x3 * wp[3] +
                        x4 * wp[4] + x5 * wp[5] + x6 * wp[6] + x7 * wp[7] + x8 * wp[8];
            const float2 ss = scsh[c];
            const float v = fmaxf(fmaf(acc, ss.x, ss.y), 0.0f);
            ushort hs, ls;
            bfsplit(v, hs, ls);
            const uint pk = ((uint)hs << 16) | (uint)ls;
            const int cc = b * 128 + c0 + c;
            if (even) h1e[(cc * 19 + y) * 10 + xi] = pk;
            else      h1o[cc * 174 + y * 9 + xi]   = pk;
        }
    }
}

// ---------------- conv2: one block per (image, co-half) --------------------
// M = 81 outputs (pad 96 = 6x16 tiles), N = 128, K = 1152 = 4 chunks x 9 taps x 32.
// 4 waves, wave-tile 48x64 (3 M-tiles x 4 N-tiles), 3 MFMAs per tile per step.
// LDS: raw chunk only: rawE 32x190 dw @0, rawO 32x174 dw @6080 (46.6 KB).
__global__ __launch_bounds__(256, 2) void k_conv2(
    const uint* __restrict__ h1e, const uint* __restrict__ h1o,
    const uint* __restrict__ Bt,
    const float* __restrict__ bias, const float* __restrict__ g,
    const float* __restrict__ bb, const float* __restrict__ bm,
    const float* __restrict__ bv, float* __restrict__ h2) {
    __shared__ uint raw[11648];
    const int t = threadIdx.x;
    const int lane = t & 63, wave = t >> 6;
    const int ln15 = lane & 15, lq = lane >> 4;
    const int wm = (wave >> 1) * 48, wn = (wave & 1) * 64;
    // XCD-pair swizzle: g and g+8 share XCD -> same image, both co-halves
    const int gg = blockIdx.x;
    const int bi  = ((gg >> 4) << 3) | (gg & 7);
    const int cot = (gg >> 3) & 1;
    const int co0 = cot * 128;

    // per-lane, per-M-tile base offsets into raw (dwords)
    int PE[3], PO[3];
#pragma unroll
    for (int i = 0; i < 3; ++i) {
        const int m = wm + i * 16 + ln15;
        const int p = m < 81 ? m : 80;       // clamp: rows 81..95 computed, not stored
        const int oh = p / 9, ow = p - oh * 9;
        PE[i] = lq * 1520 + oh * 20 + ow;            // lq*8*190 + (2oh)*10 + ow
        PO[i] = 6080 + lq * 1392 + oh * 18 + ow;     // base + lq*8*174 + (2oh)*9 + ow
    }

    f32x4 acc[3][4] = {};

    for (int c = 0; c < 4; ++c) {
        __syncthreads();
        {   // stage raw chunk (read-once): 32 ci, both parities, uint2 copies
            const uint2* se = (const uint2*)(h1e + ((size_t)bi * 128 + c * 32) * 190);
            uint2* de = (uint2*)raw;
            for (int idx = t; idx < 3040; idx += 256) de[idx] = se[idx];
            const uint2* so = (const uint2*)(h1o + ((size_t)bi * 128 + c * 32) * 174);
            uint2* dd = (uint2*)(raw + 6080);
            for (int idx = t; idx < 2784; idx += 256) dd[idx] = so[idx];
        }
        __syncthreads();
#pragma unroll
        for (int tap = 0; tap < 9; ++tap) {
            const int kh = tap / 3, kw = tap - kh * 3;
            const int odd = kw & 1;
            const int sidx = c * 9 + tap;
            // B fragments straight from global (L2-resident Bt)
            const uint* bp = Bt + (size_t)(sidx * 2 + cot) * 4096;
            short8 bh[4], bl[4];
#pragma unroll
            for (int j = 0; j < 4; ++j) {
                const int n = wn + j * 16 + ln15;
                bh[j] = *reinterpret_cast<const short8*>(bp + n * 16 + lq * 4);
                bl[j] = *reinterpret_cast<const short8*>(bp + 2048 + n * 16 + lq * 4);
            }
            const int sE = kh * 10 + (kw >> 1);
            const int sO = kh * 9;
#pragma unroll
            for (int i = 0; i < 3; ++i) {
                uint q0, q1, q2, q3, q4, q5, q6, q7;
                if (odd) {
                    const uint* rp = raw + PO[i] + sO;
                    q0 = rp[0];       q1 = rp[174];      q2 = rp[348];      q3 = rp[522];
                    q4 = rp[696];     q5 = rp[870];      q6 = rp[1044];     q7 = rp[1218];
                } else {
                    const uint* rp = raw + PE[i] + sE;
                    q0 = rp[0];       q1 = rp[190];      q2 = rp[380];      q3 = rp[570];
                    q4 = rp[760];     q5 = rp[950];      q6 = rp[1140];     q7 = rp[1330];
                }
                const short8 ah = mk8((q0 >> 16) | (q1 & 0xFFFF0000u),
                                      (q2 >> 16) | (q3 & 0xFFFF0000u),
                                      (q4 >> 16) | (q5 & 0xFFFF0000u),
                                      (q6 >> 16) | (q7 & 0xFFFF0000u));
                const short8 al = mk8((q0 & 0xFFFFu) | (q1 << 16),
                                      (q2 & 0xFFFFu) | (q3 << 16),
                                      (q4 & 0xFFFFu) | (q5 << 16),
                                      (q6 & 0xFFFFu) | (q7 << 16));
#pragma unroll
                for (int j = 0; j < 4; ++j) {
                    acc[i][j] = __builtin_amdgcn_mfma_f32_16x16x32_bf16(ah, bh[j], acc[i][j], 0, 0, 0);
                    acc[i][j] = __builtin_amdgcn_mfma_f32_16x16x32_bf16(ah, bl[j], acc[i][j], 0, 0, 0);
                    acc[i][j] = __builtin_amdgcn_mfma_f32_16x16x32_bf16(al, bh[j], acc[i][j], 0, 0, 0);
                }
            }
        }
    }

    // ---- epilogue: bn + relu, h2[bi][p][co]
    float scj[4], shj[4];
#pragma unroll
    for (int j = 0; j < 4; ++j) {
        const int co = co0 + wn + j * 16 + ln15;
        const float inv = g[co] * rsqrtf(bv[co] + 1e-5f);
        scj[j] = inv;
        shj[j] = bias[co] * inv + bb[co] - bm[co] * inv;
    }
#pragma unroll
    for (int i = 0; i < 3; ++i)
#pragma unroll
        for (int r = 0; r < 4; ++r) {
            const int m = wm + i * 16 + lq * 4 + r;
            if (m < 81) {
                float* op = h2 + (size_t)bi * 20736 + m * 256;
#pragma unroll
                for (int j = 0; j < 4; ++j) {
                    const int co = co0 + wn + j * 16 + ln15;
                    op[co] = fmaxf(fmaf(acc[i][j][r], scj[j], shj[j]), 0.0f);
                }
            }
        }
}

// ---------------- fused conv3(depthwise) + squash + 3x fccaps --------------
__device__ __forceinline__ void fccaps_block(
    const int n_l, const int n_h, const int d_h, const float* __restrict__ Wg,
    float* U, float* Uh, float* Sv, float* Av, float* Cv, float* coefs,
    float* outU, const int t) {
    const int nkd = n_h * d_h;
    const int total = n_l * nkd;
    __syncthreads();
    for (int e = t; e < total; e += 256) {
        const int i = e / nkd, rem = e - i * nkd;
        const int k = rem / d_h, l = rem - k * d_h;
        const float* wp = Wg + (size_t)((i * n_h + k) * 8) * d_h + l;
        const float* up = U + i * 8;
        float acc = 0.0f;
#pragma unroll
        for (int j = 0; j < 8; ++j) acc += up[j] * wp[j * d_h];
        Uh[e] = acc;
    }
    __syncthreads();
    for (int e = t; e < nkd; e += 256) {
        float acc = 0.0f;
        for (int i = 0; i < n_l; ++i) acc += Uh[i * nkd + e];
        Sv[e] = acc;
    }
    __syncthreads();
    for (int e = t; e < n_l * n_h; e += 256) {
        const int h = e / n_h, k = e - h * n_h;
        float acc = 0.0f;
        for (int l = 0; l < d_h; ++l)
            acc += Uh[h * nkd + k * d_h + l] * Sv[k * d_h + l];
        Av[e] = acc;
    }
    __syncthreads();
    if (t < n_l) {
        const float invs = 1.0f / 2.8284271247461903f;
        float mx = -1e30f;
        for (int k = 0; k < n_h; ++k) mx = fmaxf(mx, Av[t * n_h + k]);
        float sum = 0.0f;
        for (int k = 0; k < n_h; ++k) {
            const float ev = expf((Av[t * n_h + k] - mx) * invs);
            Cv[t * n_h + k] = ev;
            sum += ev;
        }
        const float r = 1.0f / sum;
        for (int k = 0; k < n_h; ++k) Cv[t * n_h + k] *= r;
    }
    __syncthreads();
    for (int e = t; e < nkd; e += 256) {
        const int k = e / d_h;
        float acc = 0.0f;
        for (int i = 0; i < n_l; ++i) acc += Uh[i * nkd + e] * Cv[i * n_h + k];
        Sv[e] = acc;
    }
    __syncthreads();
    if (t < n_h) {
        float ssq = 0.0f;
        for (int l = 0; l < d_h; ++l) { const float uv = Sv[t * d_h + l]; ssq += uv * uv; }
        const float n = sqrtf(ssq);
        coefs[t] = (1.0f - 1.0f / (expf(n) + 1e-20f)) / (n + 1e-20f);
    }
    __syncthreads();
    for (int e = t; e < nkd; e += 256) outU[e] = Sv[e] * coefs[e / d_h];
}

__global__ __launch_bounds__(256) void k_caps(
    const float* __restrict__ h2, const float* __restrict__ w3T,
    const float* __restrict__ b3, const float* __restrict__ W1,
    const float* __restrict__ W2, const float* __restrict__ W3,
    float* __restrict__ out) {
    __shared__ float U[256];
    __shared__ float Uh[8192];
    __shared__ float Sv[256];
    __shared__ float Av[1024];
    __shared__ float Cv[1024];
    __shared__ float coefs[32];
    const int b = blockIdx.x, t = threadIdx.x;
    {
        const float* hr = h2 + (size_t)b * 20736;
        float acc = 0.0f;
        for (int p = 0; p < 81; ++p) acc += hr[p * 256 + t] * w3T[p * 256 + t];
        U[t] = acc + b3[t];
    }
    __syncthreads();
    if (t < 32) {
        float ssq = 0.0f;
        for (int j = 0; j < 8; ++j) { const float uv = U[t * 8 + j]; ssq += uv * uv; }
        const float n = sqrtf(ssq);
        coefs[t] = (1.0f - 1.0f / (expf(n) + 1e-20f)) / (n + 1e-20f);
    }
    __syncthreads();
    U[t] *= coefs[t >> 3];
    fccaps_block(32, 32,  8, W1, U, Uh, Sv, Av, Cv, coefs, U, t);
    fccaps_block(32, 32,  8, W2, U, Uh, Sv, Av, Cv, coefs, U, t);
    fccaps_block(32, 10, 16, W3, U, Uh, Sv, Av, Cv, coefs, out + (size_t)b * 160, t);
}

// ---------------------------------------------------------------------------
extern "C" void kernel_launch(void* const* d_in, const int* in_sizes, int n_in,
                              void* d_out, int out_size, void* d_ws, size_t ws_size,
                              hipStream_t stream) {
    const float* x    = (const float*)d_in[0];
    const float* c1w  = (const float*)d_in[1];
    const float* c1b  = (const float*)d_in[2];
    const float* bn1g = (const float*)d_in[3];
    const float* bn1b = (const float*)d_in[4];
    const float* bn1m = (const float*)d_in[5];
    const float* bn1v = (const float*)d_in[6];
    const float* c2w  = (const float*)d_in[7];
    const float* c2b  = (const float*)d_in[8];
    const float* bn2g = (const float*)d_in[9];
    const float* bn2b = (const float*)d_in[10];
    const float* bn2m = (const float*)d_in[11];
    const float* bn2v = (const float*)d_in[12];
    const float* c3w  = (const float*)d_in[13];
    const float* c3b  = (const float*)d_in[14];
    const float* W1   = (const float*)d_in[15];
    const float* W2   = (const float*)d_in[16];
    const float* W3   = (const float*)d_in[17];
    float* out = (float*)d_out;
    uint*  wsu = (uint*)d_ws;
    float* wsf = (float*)d_ws;

    uint*  h1e = wsu;                    // 12,451,840 dw
    uint*  h1o = wsu + 12451840;         // 11,403,264 dw
    float* h2  = wsf + 23855104;         // 10,616,832 dw
    uint*  Bt  = wsu + 34471936;         //    294,912 dw
    float* w3T = wsf + 34766848;         //     20,736 dw

    k_prep_b<<<dim3(36, 4), 256, 0, stream>>>(c2w, Bt);
    k_prep_w3<<<dim3(81), 256, 0, stream>>>(c3w, w3T);
    k_conv1<<<dim3(512, 8), 256, 0, stream>>>(x, c1w, c1b, bn1g, bn1b, bn1m, bn1v, h1e, h1o);
    k_conv2<<<dim3(1024), 256, 0, stream>>>(h1e, h1o, Bt, c2b, bn2g, bn2b, bn2m, bn2v, h2);
    k_caps<<<dim3(512), 256, 0, stream>>>(h2, w3T, c3b, W1, W2, W3, out);
}

// Round 4
// 276.113 us; speedup vs baseline: 1.9066x; 1.0600x over previous
//
#include <hip/hip_runtime.h>

// ---------------------------------------------------------------------------
// DeepCapsNet forward. conv2 = MFMA (bf16 hh+hl+lh split). The hi/lo split is
// now a *layout* property: conv1 emits 4 bf16 planes (hiE/hiO/loE/loO) with
// ci-octet-innermost order, grouped per (image,chunk) into one contiguous
// 46.2KB block == the conv2 LDS image. A-frags = single ds_read_b128.
// Workspace layout (dwords):
//   h1 : [0,        23658496)  ushort bf16, per (bi,chunk=ci/32) block of
//        11552 dw: hiE[4][190][8] | hiO[4][171][8] | loE | loO
//   h2 : [23658496, 34275328)  f32, [b][p=81][co=256]
//   Bt : [34275328, 34570240)  u32, [sidx=chunk*9+tap][cot][hi/lo][n=128][16dw]
//   w3T: [34570240, 34590976)  f32, [p=81][c=256]
// total 138,363,904 bytes
// ---------------------------------------------------------------------------

typedef __attribute__((ext_vector_type(8))) short short8;   // 8 bf16
typedef __attribute__((ext_vector_type(4))) float f32x4;

__device__ __forceinline__ ushort f2bf(float x) {
    uint u = __float_as_uint(x);
    return (ushort)((u + 0x7FFFu + ((u >> 16) & 1u)) >> 16);
}
__device__ __forceinline__ void bfsplit(float x, ushort& h, ushort& l) {
    h = f2bf(x);
    float hf = __uint_as_float(((uint)h) << 16);
    l = f2bf(x - hf);
}

// ---------------- prep: w2 -> Bt pre-tiled bf16 hi/lo fragment images ------
__global__ __launch_bounds__(256) void k_prep_b(
    const float* __restrict__ w2, uint* __restrict__ Bt) {
    __shared__ __align__(16) float wbuf[64 * 288];
    const int sidx = blockIdx.x;          // 0..35
    const int coq  = blockIdx.y;          // 0..3
    const int t = threadIdx.x;
    const int chunk = sidx / 9, tap = sidx - chunk * 9;
    const int co0 = coq * 64;
    for (int idx = t; idx < 4608; idx += 256) {
        const int n = idx / 72, q = idx - n * 72;
        ((float4*)wbuf)[n * 72 + q] =
            *(const float4*)(w2 + (size_t)(co0 + n) * 1152 + chunk * 288 + q * 4);
    }
    __syncthreads();
    const int n = t & 63, dg = (t >> 6) * 4;
    const int cot = coq >> 1, nn = ((coq & 1) * 64) + n;
    uint* dst = Bt + (size_t)(sidx * 2 + cot) * 4096;
#pragma unroll
    for (int dd = 0; dd < 4; ++dd) {
        const int d = dg + dd;
        const float x = wbuf[n * 288 + (2 * d) * 9 + tap];
        const float y = wbuf[n * 288 + (2 * d + 1) * 9 + tap];
        ushort xh, xl, yh, yl;
        bfsplit(x, xh, xl);
        bfsplit(y, yh, yl);
        dst[nn * 16 + d]        = (uint)xh | ((uint)yh << 16);
        dst[2048 + nn * 16 + d] = (uint)xl | ((uint)yl << 16);
    }
}

// ---------------- prep: w3(c,81) -> w3T(p,c) -------------------------------
__global__ __launch_bounds__(256) void k_prep_w3(
    const float* __restrict__ w3, float* __restrict__ w3T) {
    const int p = blockIdx.x, t = threadIdx.x;
    w3T[p * 256 + t] = w3[t * 81 + p];
}

// ---------------- conv1: one block per image, bf16 plane output ------------
// out per (bi,chunk) block (ushort offsets within 23104-ushort block):
//   hiE: o*1520 + posE*8   hiO: 6080  + o*1368 + posO*8
//   loE: 11552 + o*1520 + posE*8   loO: 17632 + o*1368 + posO*8
__global__ __launch_bounds__(256) void k_conv1(
    const float* __restrict__ x, const float* __restrict__ w,
    const float* __restrict__ bias, const float* __restrict__ g,
    const float* __restrict__ bb, const float* __restrict__ bm,
    const float* __restrict__ bv, ushort* __restrict__ h1) {
    __shared__ __align__(16) float xs[1521];
    __shared__ float wls[1152];
    __shared__ float2 scsh[128];
    const int b = blockIdx.x, t = threadIdx.x;
    const float* xb = x + (size_t)b * 1521;
    for (int i = t; i < 1521; i += 256) xs[i] = xb[i];
    for (int i = t; i < 1152; i += 256) wls[i] = w[i];
    if (t < 128) {
        const float inv = g[t] * rsqrtf(bv[t] + 1e-5f);
        scsh[t] = make_float2(inv, bias[t] * inv + bb[t] - bm[t] * inv);
    }
    __syncthreads();
    ushort* ib = h1 + (size_t)b * 92416;
#pragma unroll
    for (int f = 0; f < 2; ++f) {
        const int p = t + 256 * f;
        if (p >= 361) break;
        const int y = p / 19, xq = p - y * 19;
        const int base = y * 78 + xq * 2;
        const float x0 = xs[base],      x1 = xs[base + 1],  x2 = xs[base + 2];
        const float x3 = xs[base + 39], x4 = xs[base + 40], x5 = xs[base + 41];
        const float x6 = xs[base + 78], x7 = xs[base + 79], x8 = xs[base + 80];
        const int even = ((xq & 1) == 0);
        const int xi = xq >> 1;
        const int posE = y * 10 + xi, posO = y * 9 + xi;
#pragma unroll
        for (int oc = 0; oc < 16; ++oc) {
            short8 hs, ls;
#pragma unroll
            for (int j = 0; j < 8; ++j) {
                const int c = oc * 8 + j;
                const float* wp = wls + c * 9;
                float acc = x0 * wp[0] + x1 * wp[1] + x2 * wp[2] + x3 * wp[3] +
                            x4 * wp[4] + x5 * wp[5] + x6 * wp[6] + x7 * wp[7] + x8 * wp[8];
                const float2 ss = scsh[c];
                const float v = fmaxf(fmaf(acc, ss.x, ss.y), 0.0f);
                ushort hh, lw;
                bfsplit(v, hh, lw);
                hs[j] = (short)hh;
                ls[j] = (short)lw;
            }
            const int chunk = oc >> 2, o = oc & 3;
            ushort* cb = ib + chunk * 23104;
            if (even) {
                *(short8*)(cb + o * 1520 + posE * 8)         = hs;
                *(short8*)(cb + 11552 + o * 1520 + posE * 8) = ls;
            } else {
                *(short8*)(cb + 6080 + o * 1368 + posO * 8)  = hs;
                *(short8*)(cb + 17632 + o * 1368 + posO * 8) = ls;
            }
        }
    }
}

// ---------------- conv2: one block per (image, co-half) --------------------
// M=81 (pad 96), N=128, K = 4 chunks x 9 taps x 32ci. 4 waves, wave 48x64.
// LDS = one (bi,chunk) h1 block verbatim: 11552 dw = 46.2 KB -> 3 blocks/CU.
// LDS dw offsets: hiE 0 [o][190][4] | hiO 3040 [o][171][4] | loE 5776 | loO 8816
__global__ __launch_bounds__(256, 3) void k_conv2(
    const uint* __restrict__ h1u, const uint* __restrict__ Bt,
    const float* __restrict__ bias, const float* __restrict__ g,
    const float* __restrict__ bb, const float* __restrict__ bm,
    const float* __restrict__ bv, float* __restrict__ h2) {
    __shared__ __align__(16) uint raw[11552];
    const int t = threadIdx.x;
    const int lane = t & 63, wave = t >> 6;
    const int ln15 = lane & 15, lq = lane >> 4;
    const int wm = (wave >> 1) * 48, wn = (wave & 1) * 64;
    // XCD-pair swizzle: gg and gg+8 share an XCD -> same image, both co-halves
    const int gg = blockIdx.x;
    const int bi  = ((gg >> 4) << 3) | (gg & 7);
    const int cot = (gg >> 3) & 1;
    const int co0 = cot * 128;

    int PE[3], PO[3];
#pragma unroll
    for (int i = 0; i < 3; ++i) {
        const int m = wm + i * 16 + ln15;
        const int p = m < 81 ? m : 80;       // pad rows clamp (computed, not stored)
        const int oh = p / 9, ow = p - oh * 9;
        PE[i] = lq * 760 + oh * 80 + ow * 4;
        PO[i] = 3040 + lq * 684 + oh * 72 + ow * 4;
    }

    f32x4 acc[3][4] = {};

    for (int c = 0; c < 4; ++c) {
        __syncthreads();
        {   // stage the whole (bi,chunk) block: one flat contiguous copy
            const uint4* src = (const uint4*)(h1u + (size_t)(bi * 4 + c) * 11552);
            uint4* dst = (uint4*)raw;
            for (int idx = t; idx < 2888; idx += 256) dst[idx] = src[idx];
        }
        __syncthreads();
#pragma unroll
        for (int tap = 0; tap < 9; ++tap) {
            const int kh = tap / 3, kw = tap - kh * 3;
            const int odd = kw & 1;
            const int sidx = c * 9 + tap;
            const uint* bp = Bt + (size_t)(sidx * 2 + cot) * 4096;
            short8 bh[4], bl[4];
#pragma unroll
            for (int j = 0; j < 4; ++j) {
                const int n = wn + j * 16 + ln15;
                bh[j] = *reinterpret_cast<const short8*>(bp + n * 16 + lq * 4);
                bl[j] = *reinterpret_cast<const short8*>(bp + 2048 + n * 16 + lq * 4);
            }
            const int sE = kh * 40 + (kw >> 1) * 4;
            const int sO = kh * 36;
#pragma unroll
            for (int i = 0; i < 3; ++i) {
                const int addr = odd ? (PO[i] + sO) : (PE[i] + sE);
                const short8 ah = *reinterpret_cast<const short8*>(raw + addr);
                const short8 al = *reinterpret_cast<const short8*>(raw + addr + 5776);
#pragma unroll
                for (int j = 0; j < 4; ++j) {
                    acc[i][j] = __builtin_amdgcn_mfma_f32_16x16x32_bf16(ah, bh[j], acc[i][j], 0, 0, 0);
                    acc[i][j] = __builtin_amdgcn_mfma_f32_16x16x32_bf16(ah, bl[j], acc[i][j], 0, 0, 0);
                    acc[i][j] = __builtin_amdgcn_mfma_f32_16x16x32_bf16(al, bh[j], acc[i][j], 0, 0, 0);
                }
            }
        }
    }

    // ---- epilogue: bn + relu, h2[bi][p][co]
    float scj[4], shj[4];
#pragma unroll
    for (int j = 0; j < 4; ++j) {
        const int co = co0 + wn + j * 16 + ln15;
        const float inv = g[co] * rsqrtf(bv[co] + 1e-5f);
        scj[j] = inv;
        shj[j] = bias[co] * inv + bb[co] - bm[co] * inv;
    }
#pragma unroll
    for (int i = 0; i < 3; ++i)
#pragma unroll
        for (int r = 0; r < 4; ++r) {
            const int m = wm + i * 16 + lq * 4 + r;
            if (m < 81) {
                float* op = h2 + (size_t)bi * 20736 + m * 256;
#pragma unroll
                for (int j = 0; j < 4; ++j) {
                    const int co = co0 + wn + j * 16 + ln15;
                    op[co] = fmaxf(fmaf(acc[i][j][r], scj[j], shj[j]), 0.0f);
                }
            }
        }
}

// ---------------- fused conv3(depthwise) + squash + 3x fccaps --------------
__device__ __forceinline__ void fccaps_block(
    const int n_l, const int n_h, const int d_h, const float* __restrict__ Wg,
    float* U, float* Uh, float* Sv, float* Av, float* Cv, float* coefs,
    float* outU, const int t) {
    const int nkd = n_h * d_h;
    const int total = n_l * nkd;
    __syncthreads();
    for (int e = t; e < total; e += 256) {
        const int i = e / nkd, rem = e - i * nkd;
        const int k = rem / d_h, l = rem - k * d_h;
        const float* wp = Wg + (size_t)((i * n_h + k) * 8) * d_h + l;
        const float* up = U + i * 8;
        float acc = 0.0f;
#pragma unroll
        for (int j = 0; j < 8; ++j) acc += up[j] * wp[j * d_h];
        Uh[e] = acc;
    }
    __syncthreads();
    for (int e = t; e < nkd; e += 256) {
        float acc = 0.0f;
        for (int i = 0; i < n_l; ++i) acc += Uh[i * nkd + e];
        Sv[e] = acc;
    }
    __syncthreads();
    for (int e = t; e < n_l * n_h; e += 256) {
        const int h = e / n_h, k = e - h * n_h;
        float acc = 0.0f;
        for (int l = 0; l < d_h; ++l)
            acc += Uh[h * nkd + k * d_h + l] * Sv[k * d_h + l];
        Av[e] = acc;
    }
    __syncthreads();
    if (t < n_l) {
        const float invs = 1.0f / 2.8284271247461903f;
        float mx = -1e30f;
        for (int k = 0; k < n_h; ++k) mx = fmaxf(mx, Av[t * n_h + k]);
        float sum = 0.0f;
        for (int k = 0; k < n_h; ++k) {
            const float ev = expf((Av[t * n_h + k] - mx) * invs);
            Cv[t * n_h + k] = ev;
            sum += ev;
        }
        const float r = 1.0f / sum;
        for (int k = 0; k < n_h; ++k) Cv[t * n_h + k] *= r;
    }
    __syncthreads();
    for (int e = t; e < nkd; e += 256) {
        const int k = e / d_h;
        float acc = 0.0f;
        for (int i = 0; i < n_l; ++i) acc += Uh[i * nkd + e] * Cv[i * n_h + k];
        Sv[e] = acc;
    }
    __syncthreads();
    if (t < n_h) {
        float ssq = 0.0f;
        for (int l = 0; l < d_h; ++l) { const float uv = Sv[t * d_h + l]; ssq += uv * uv; }
        const float n = sqrtf(ssq);
        coefs[t] = (1.0f - 1.0f / (expf(n) + 1e-20f)) / (n + 1e-20f);
    }
    __syncthreads();
    for (int e = t; e < nkd; e += 256) outU[e] = Sv[e] * coefs[e / d_h];
}

__global__ __launch_bounds__(256) void k_caps(
    const float* __restrict__ h2, const float* __restrict__ w3T,
    const float* __restrict__ b3, const float* __restrict__ W1,
    const float* __restrict__ W2, const float* __restrict__ W3,
    float* __restrict__ out) {
    __shared__ float U[256];
    __shared__ float Uh[8192];
    __shared__ float Sv[256];
    __shared__ float Av[1024];
    __shared__ float Cv[1024];
    __shared__ float coefs[32];
    const int b = blockIdx.x, t = threadIdx.x;
    {
        const float* hr = h2 + (size_t)b * 20736;
        float acc = 0.0f;
        for (int p = 0; p < 81; ++p) acc += hr[p * 256 + t] * w3T[p * 256 + t];
        U[t] = acc + b3[t];
    }
    __syncthreads();
    if (t < 32) {
        float ssq = 0.0f;
        for (int j = 0; j < 8; ++j) { const float uv = U[t * 8 + j]; ssq += uv * uv; }
        const float n = sqrtf(ssq);
        coefs[t] = (1.0f - 1.0f / (expf(n) + 1e-20f)) / (n + 1e-20f);
    }
    __syncthreads();
    U[t] *= coefs[t >> 3];
    fccaps_block(32, 32,  8, W1, U, Uh, Sv, Av, Cv, coefs, U, t);
    fccaps_block(32, 32,  8, W2, U, Uh, Sv, Av, Cv, coefs, U, t);
    fccaps_block(32, 10, 16, W3, U, Uh, Sv, Av, Cv, coefs, out + (size_t)b * 160, t);
}

// ---------------------------------------------------------------------------
extern "C" void kernel_launch(void* const* d_in, const int* in_sizes, int n_in,
                              void* d_out, int out_size, void* d_ws, size_t ws_size,
                              hipStream_t stream) {
    const float* x    = (const float*)d_in[0];
    const float* c1w  = (const float*)d_in[1];
    const float* c1b  = (const float*)d_in[2];
    const float* bn1g = (const float*)d_in[3];
    const float* bn1b = (const float*)d_in[4];
    const float* bn1m = (const float*)d_in[5];
    const float* bn1v = (const float*)d_in[6];
    const float* c2w  = (const float*)d_in[7];
    const float* c2b  = (const float*)d_in[8];
    const float* bn2g = (const float*)d_in[9];
    const float* bn2b = (const float*)d_in[10];
    const float* bn2m = (const float*)d_in[11];
    const float* bn2v = (const float*)d_in[12];
    const float* c3w  = (const float*)d_in[13];
    const float* c3b  = (const float*)d_in[14];
    const float* W1   = (const float*)d_in[15];
    const float* W2   = (const float*)d_in[16];
    const float* W3   = (const float*)d_in[17];
    float* out = (float*)d_out;
    uint*  wsu = (uint*)d_ws;
    float* wsf = (float*)d_ws;

    ushort* h1  = (ushort*)wsu;          // 23,658,496 dw as bf16 planes
    float*  h2  = wsf + 23658496;        // 10,616,832 dw
    uint*   Bt  = wsu + 34275328;        //    294,912 dw
    float*  w3T = wsf + 34570240;        //     20,736 dw

    k_prep_b<<<dim3(36, 4), 256, 0, stream>>>(c2w, Bt);
    k_prep_w3<<<dim3(81), 256, 0, stream>>>(c3w, w3T);
    k_conv1<<<dim3(512), 256, 0, stream>>>(x, c1w, c1b, bn1g, bn1b, bn1m, bn1v, h1);
    k_conv2<<<dim3(1024), 256, 0, stream>>>((const uint*)h1, Bt, c2b, bn2g, bn2b, bn2m, bn2v, h2);
    k_caps<<<dim3(512), 256, 0, stream>>>(h2, w3T, c3b, W1, W2, W3, out);
}